// Round 3
// baseline (544.248 us; speedup 1.0000x reference)
//
#include <hip/hip_runtime.h>
#include <stdint.h>

#define SEQ 2048
#define DIM 2048
#define NH 16
#define HD 128

typedef __attribute__((ext_vector_type(8))) short short8;
typedef __attribute__((ext_vector_type(4))) float f32x4;

#define MFMA(a, b, c) __builtin_amdgcn_mfma_f32_16x16x32_bf16((a), (b), (c), 0, 0, 0)

#define GL2LDS(gp, lp)                                                              \
    __builtin_amdgcn_global_load_lds(                                               \
        (const __attribute__((address_space(1))) void*)(gp),                        \
        (__attribute__((address_space(3))) void*)(lp), 16, 0, 0)

__device__ __forceinline__ unsigned short f2bf(float f) {
    unsigned u = __builtin_bit_cast(unsigned, f);
    u += 0x7FFFu + ((u >> 16) & 1u);  // RNE
    return (unsigned short)(u >> 16);
}

__device__ __forceinline__ short8 lds_ld8(const unsigned short* p) {
    return *(const short8*)p;
}

// ---------------- fp32 -> bf16 convert (x + 4 weights fused) ----------------
__global__ void cvt_all(const float* __restrict__ x, const float* __restrict__ wq,
                        const float* __restrict__ wk, const float* __restrict__ wv,
                        const float* __restrict__ wo, unsigned short* __restrict__ xb,
                        unsigned short* __restrict__ wqb, unsigned short* __restrict__ wkb,
                        unsigned short* __restrict__ wvb, unsigned short* __restrict__ wob) {
    int sel = blockIdx.x >> 11;          // 2048 blocks per tensor
    int lb = blockIdx.x & 2047;
    const float* src = sel == 0 ? x : sel == 1 ? wq : sel == 2 ? wk : sel == 3 ? wv : wo;
    unsigned short* dst = sel == 0 ? xb : sel == 1 ? wqb : sel == 2 ? wkb : sel == 3 ? wvb : wob;
    size_t i = ((size_t)lb * 256 + threadIdx.x) * 8;  // 2048*256*8 = 4M elems
    const f32x4* p = (const f32x4*)(src + i);
    f32x4 a = p[0], b = p[1];
    short8 r;
    r[0] = (short)f2bf(a[0]); r[1] = (short)f2bf(a[1]);
    r[2] = (short)f2bf(a[2]); r[3] = (short)f2bf(a[3]);
    r[4] = (short)f2bf(b[0]); r[5] = (short)f2bf(b[1]);
    r[6] = (short)f2bf(b[2]); r[7] = (short)f2bf(b[3]);
    *(short8*)(dst + i) = r;
}

// ---------------- fused QKV GEMM: C[2048,2048] = xb · W^T, 128x128 tile -----
// part 0/1 (Q,K): natural bf16 [seq][dim] output.
// part 2 (V): transposed output vt[head][d][seq] via LDS transpose.
__global__ __launch_bounds__(256, 3) void gemm_qkv(
    const unsigned short* __restrict__ xb, const unsigned short* __restrict__ wqb,
    const unsigned short* __restrict__ wkb, const unsigned short* __restrict__ wvb,
    unsigned short* __restrict__ qo, unsigned short* __restrict__ ko,
    unsigned short* __restrict__ vto) {
    __shared__ unsigned short lds[17408];  // staging: A[0..8191], B[8192..16383]; epilogue reuses all
    unsigned short* Alds = lds;
    unsigned short* Blds = lds + 8192;

    const int tid = threadIdx.x;
    const int bid = blockIdx.x;
    const int mb = bid & 15;
    const int nb = bid >> 4;            // 0..47
    const int part = nb >> 4;           // 0=q 1=k 2=v
    const int nloc = (nb & 15) << 7;
    const unsigned short* __restrict__ B = part == 0 ? wqb : (part == 1 ? wkb : wvb);
    const int m0 = mb << 7;

    const int w = tid >> 6, l = tid & 63;
    const int wr = (w >> 1) * 64, wc = (w & 1) * 64;
    const int lr = l & 15, lk = l >> 4;

    f32x4 z = {0.f, 0.f, 0.f, 0.f};
    f32x4 acc[4][4];
#pragma unroll
    for (int i = 0; i < 4; i++)
#pragma unroll
        for (int j = 0; j < 4; j++) acc[i][j] = z;

    const int srow = tid >> 3;   // 0..31
    const int schunk = tid & 7;  // 16B chunk within 128B row

    for (int kt = 0; kt < DIM; kt += 64) {
        __syncthreads();
#pragma unroll
        for (int i = 0; i < 4; i++) {
            int row = i * 32 + srow;
            int gc = (schunk ^ (row & 7)) * 8;  // inverse-swizzled global source (rule #21)
            GL2LDS(xb + (size_t)(m0 + row) * DIM + kt + gc, Alds + i * 2048 + tid * 8);
            GL2LDS(B + (size_t)(nloc + row) * DIM + kt + gc, Blds + i * 2048 + tid * 8);
        }
        __syncthreads();
#pragma unroll
        for (int ks = 0; ks < 2; ks++) {
            short8 af[4], bf[4];
#pragma unroll
            for (int mf = 0; mf < 4; mf++) {
                int ra = wr + mf * 16 + lr;
                af[mf] = lds_ld8(&Alds[ra * 64 + (((ks * 4 + lk) ^ (ra & 7)) * 8)]);
            }
#pragma unroll
            for (int nf = 0; nf < 4; nf++) {
                int rb = wc + nf * 16 + lr;
                bf[nf] = lds_ld8(&Blds[rb * 64 + (((ks * 4 + lk) ^ (rb & 7)) * 8)]);
            }
#pragma unroll
            for (int mf = 0; mf < 4; mf++)
#pragma unroll
                for (int nf = 0; nf < 4; nf++) acc[mf][nf] = MFMA(af[mf], bf[nf], acc[mf][nf]);
        }
    }

    if (part < 2) {
        unsigned short* dst = part == 0 ? qo : ko;
#pragma unroll
        for (int mf = 0; mf < 4; mf++)
#pragma unroll
            for (int nf = 0; nf < 4; nf++)
#pragma unroll
                for (int r = 0; r < 4; r++) {
                    int row = m0 + wr + mf * 16 + lk * 4 + r;
                    int col = nloc + wc + nf * 16 + lr;
                    dst[(size_t)row * DIM + col] = f2bf(acc[mf][nf][r]);
                }
    } else {
        const int head = nb & 15;
        __syncthreads();  // staging LDS free now
        // write transposed into LDS: T[d][s], row stride 136 (pad -> 2-way banks)
#pragma unroll
        for (int mf = 0; mf < 4; mf++)
#pragma unroll
            for (int nf = 0; nf < 4; nf++)
#pragma unroll
                for (int r = 0; r < 4; r++) {
                    int d = wc + nf * 16 + lr;
                    int s = wr + mf * 16 + lk * 4 + r;
                    lds[d * 136 + s] = f2bf(acc[mf][nf][r]);
                }
        __syncthreads();
#pragma unroll
        for (int i = 0; i < 8; i++) {
            int d = (tid >> 4) + i * 16;
            int c = tid & 15;
            short8 v = *(const short8*)&lds[d * 136 + c * 8];
            *(short8*)(vto + (size_t)(head * 128 + d) * SEQ + m0 + c * 8) = v;
        }
    }
}

// ---------------- flash attention: 1 block = (head, 64 q rows), 4 waves -----
__global__ __launch_bounds__(256, 2) void attn_kernel(
    const unsigned short* __restrict__ qg, const unsigned short* __restrict__ kg,
    const unsigned short* __restrict__ vtg, const float* __restrict__ mask,
    unsigned short* __restrict__ ao) {
    __shared__ unsigned short Klds[64 * 136];   // K[kv][d], padded
    __shared__ unsigned short Vlds[128 * 72];   // Vt[d][kv], padded
    __shared__ unsigned short Plds[4][16 * 72]; // per-wave P[q][kv], padded

    const int bid = blockIdx.x;
    const int h = bid >> 5;
    const int q0 = (bid & 31) << 6;
    const int tid = threadIdx.x;
    const int w = tid >> 6, l = tid & 63;
    const int lr = l & 15, lk = l >> 4;

    const float sc = 0.08838834764831845f * 1.4426950408889634f;  // 1/sqrt(128) * log2e
    const float l2e = 1.4426950408889634f;

    // Q fragments in registers (A operand), row = q0 + w*16 + lr
    short8 qf[4];
    {
        const unsigned short* qp = qg + (size_t)(q0 + w * 16 + lr) * DIM + h * 128;
#pragma unroll
        for (int ks = 0; ks < 4; ks++) qf[ks] = *(const short8*)(qp + ks * 32 + lk * 8);
    }

    f32x4 z = {0.f, 0.f, 0.f, 0.f};
    f32x4 oacc[8];
#pragma unroll
    for (int i = 0; i < 8; i++) oacc[i] = z;
    float m_r[4] = {-3.0e38f, -3.0e38f, -3.0e38f, -3.0e38f};
    float l_r[4] = {0.f, 0.f, 0.f, 0.f};

    for (int kv0 = 0; kv0 < SEQ; kv0 += 64) {
        __syncthreads();
        // stage K tile [64][128]
#pragma unroll
        for (int i = 0; i < 4; i++) {
            int r = i * 16 + (tid >> 4), c = tid & 15;
            *(short8*)&Klds[r * 136 + c * 8] =
                *(const short8*)(kg + (size_t)(kv0 + r) * DIM + h * 128 + c * 8);
        }
        // stage Vt tile [128][64]
#pragma unroll
        for (int i = 0; i < 4; i++) {
            int d = i * 32 + (tid >> 3), c = tid & 7;
            *(short8*)&Vlds[d * 72 + c * 8] =
                *(const short8*)(vtg + (size_t)(h * 128 + d) * SEQ + kv0 + c * 8);
        }
        __syncthreads();

        // S = Q K^T  (per wave: 16q x 64kv)
        f32x4 sacc[4];
#pragma unroll
        for (int kvf = 0; kvf < 4; kvf++) sacc[kvf] = z;
#pragma unroll
        for (int ks = 0; ks < 4; ks++)
#pragma unroll
            for (int kvf = 0; kvf < 4; kvf++) {
                short8 kf = lds_ld8(&Klds[(kvf * 16 + lr) * 136 + ks * 32 + lk * 8]);
                sacc[kvf] = MFMA(qf[ks], kf, sacc[kvf]);
            }

        // mask load (64B contiguous per 16-lane group)
        const float* mrow = mask + ((size_t)h * SEQ + (q0 + w * 16 + lk * 4)) * SEQ + kv0 + lr;
        float mv[4][4];
#pragma unroll
        for (int r = 0; r < 4; r++)
#pragma unroll
            for (int kvf = 0; kvf < 4; kvf++) mv[r][kvf] = mrow[(size_t)r * SEQ + kvf * 16];

        // scores in log2-domain
        float sv[4][4];  // [kvf][r]
#pragma unroll
        for (int kvf = 0; kvf < 4; kvf++)
#pragma unroll
            for (int r = 0; r < 4; r++) sv[kvf][r] = sacc[kvf][r] * sc + mv[r][kvf] * l2e;

        // online softmax: row max (cross-lane within 16-group), rescale factor
        float fr[4];
#pragma unroll
        for (int r = 0; r < 4; r++) {
            float mx = fmaxf(fmaxf(sv[0][r], sv[1][r]), fmaxf(sv[2][r], sv[3][r]));
            mx = fmaxf(mx, __shfl_xor(mx, 1));
            mx = fmaxf(mx, __shfl_xor(mx, 2));
            mx = fmaxf(mx, __shfl_xor(mx, 4));
            mx = fmaxf(mx, __shfl_xor(mx, 8));
            float mnew = fmaxf(m_r[r], mx);
            fr[r] = exp2f(m_r[r] - mnew);
            m_r[r] = mnew;
        }
        // P = exp2(s - m), per-lane partial row sums, write P to LDS (bf16)
#pragma unroll
        for (int r = 0; r < 4; r++) {
            float ps = 0.f;
#pragma unroll
            for (int kvf = 0; kvf < 4; kvf++) {
                float p = exp2f(sv[kvf][r] - m_r[r]);
                ps += p;
                Plds[w][(lk * 4 + r) * 72 + kvf * 16 + lr] = f2bf(p);
            }
            l_r[r] = l_r[r] * fr[r] + ps;
        }
        // rescale O accumulator
#pragma unroll
        for (int dn = 0; dn < 8; dn++)
#pragma unroll
            for (int r = 0; r < 4; r++) oacc[dn][r] *= fr[r];

        // O += P · V  (B operand from transposed V: k-contiguous)
#pragma unroll
        for (int ksl = 0; ksl < 2; ksl++) {
            short8 pa = lds_ld8(&Plds[w][lr * 72 + ksl * 32 + lk * 8]);
#pragma unroll
            for (int dn = 0; dn < 8; dn++) {
                short8 vb = lds_ld8(&Vlds[(dn * 16 + lr) * 72 + ksl * 32 + lk * 8]);
                oacc[dn] = MFMA(pa, vb, oacc[dn]);
            }
        }
    }

    // final row-sum reduce + normalize + store bf16
#pragma unroll
    for (int r = 0; r < 4; r++) {
        float s = l_r[r];
        s += __shfl_xor(s, 1);
        s += __shfl_xor(s, 2);
        s += __shfl_xor(s, 4);
        s += __shfl_xor(s, 8);
        l_r[r] = 1.0f / s;
    }
    const int orow = q0 + w * 16 + lk * 4;
#pragma unroll
    for (int dn = 0; dn < 8; dn++)
#pragma unroll
        for (int r = 0; r < 4; r++)
            ao[(size_t)(orow + r) * DIM + h * 128 + dn * 16 + lr] = f2bf(oacc[dn][r] * l_r[r]);
}

// ---------------- output projection: out[2048,2048] f32 = ao · wo^T ---------
// 128x64 tile -> 512 blocks (2/CU)
__global__ __launch_bounds__(256, 3) void gemm_o(const unsigned short* __restrict__ ao,
                                                 const unsigned short* __restrict__ wob,
                                                 float* __restrict__ out) {
    __shared__ unsigned short lds[8192 + 4096];  // A 128x64, B 64x64
    unsigned short* Alds = lds;
    unsigned short* Blds = lds + 8192;

    const int tid = threadIdx.x;
    const int bid = blockIdx.x;
    const int mb = bid & 15;
    const int nb = bid >> 4;  // 0..31
    const int m0 = mb << 7, n0 = nb << 6;

    const int w = tid >> 6, l = tid & 63;
    const int wr = (w >> 1) * 64, wc = (w & 1) * 32;
    const int lr = l & 15, lk = l >> 4;

    f32x4 z = {0.f, 0.f, 0.f, 0.f};
    f32x4 acc[4][2];
#pragma unroll
    for (int i = 0; i < 4; i++) {
        acc[i][0] = z;
        acc[i][1] = z;
    }

    const int srow = tid >> 3;
    const int schunk = tid & 7;

    for (int kt = 0; kt < DIM; kt += 64) {
        __syncthreads();
#pragma unroll
        for (int i = 0; i < 4; i++) {
            int row = i * 32 + srow;
            int gc = (schunk ^ (row & 7)) * 8;
            GL2LDS(ao + (size_t)(m0 + row) * DIM + kt + gc, Alds + i * 2048 + tid * 8);
        }
#pragma unroll
        for (int i = 0; i < 2; i++) {
            int row = i * 32 + srow;
            int gc = (schunk ^ (row & 7)) * 8;
            GL2LDS(wob + (size_t)(n0 + row) * DIM + kt + gc, Blds + i * 2048 + tid * 8);
        }
        __syncthreads();
#pragma unroll
        for (int ks = 0; ks < 2; ks++) {
            short8 af[4], bf[2];
#pragma unroll
            for (int mf = 0; mf < 4; mf++) {
                int ra = wr + mf * 16 + lr;
                af[mf] = lds_ld8(&Alds[ra * 64 + (((ks * 4 + lk) ^ (ra & 7)) * 8)]);
            }
#pragma unroll
            for (int nf = 0; nf < 2; nf++) {
                int rb = wc + nf * 16 + lr;
                bf[nf] = lds_ld8(&Blds[rb * 64 + (((ks * 4 + lk) ^ (rb & 7)) * 8)]);
            }
#pragma unroll
            for (int mf = 0; mf < 4; mf++)
#pragma unroll
                for (int nf = 0; nf < 2; nf++) acc[mf][nf] = MFMA(af[mf], bf[nf], acc[mf][nf]);
        }
    }

#pragma unroll
    for (int mf = 0; mf < 4; mf++)
#pragma unroll
        for (int nf = 0; nf < 2; nf++)
#pragma unroll
            for (int r = 0; r < 4; r++) {
                int row = m0 + wr + mf * 16 + lk * 4 + r;
                int col = n0 + wc + nf * 16 + lr;
                out[(size_t)row * DIM + col] = acc[mf][nf][r];
            }
}

extern "C" void kernel_launch(void* const* d_in, const int* in_sizes, int n_in, void* d_out,
                              int out_size, void* d_ws, size_t ws_size, hipStream_t stream) {
    const float* x = (const float*)d_in[0];
    const float* mask = (const float*)d_in[1];
    // d_in[2] = start_pos (0, ignored)
    const float* wq = (const float*)d_in[3];
    const float* wk = (const float*)d_in[4];
    const float* wv = (const float*)d_in[5];
    const float* wo = (const float*)d_in[6];
    float* out = (float*)d_out;

    const size_t NE = (size_t)SEQ * DIM;  // 4M elements
    // Workspace layout: 8 slots x 8 MB = 64 MiB. ao reuses the wqb slot
    // (wqb's last reader, gemm_qkv, completes before attn_kernel starts).
    const size_t NEEDED = 8 * NE * sizeof(unsigned short);  // 67,108,864 B
    if (ws_size < NEEDED) {
        // Insufficient scratch: launch nothing -> clean correctness failure
        // (diagnostic), never an out-of-bounds write (container-killer).
        return;
    }
    unsigned short* xb = (unsigned short*)d_ws;
    unsigned short* wqb = xb + NE;
    unsigned short* wkb = wqb + NE;
    unsigned short* wvb = wkb + NE;
    unsigned short* wob = wvb + NE;
    unsigned short* qo = wob + NE;
    unsigned short* ko = qo + NE;
    unsigned short* vto = ko + NE;
    unsigned short* ao = wqb;  // slot reuse

    cvt_all<<<5 * 2048, 256, 0, stream>>>(x, wq, wk, wv, wo, xb, wqb, wkb, wvb, wob);
    gemm_qkv<<<768, 256, 0, stream>>>(xb, wqb, wkb, wvb, qo, ko, vto);
    attn_kernel<<<512, 256, 0, stream>>>(qo, ko, vto, mask, ao);
    gemm_o<<<512, 256, 0, stream>>>(ao, wob, out);
}